// Round 7
// baseline (500.298 us; speedup 1.0000x reference)
//
#include <hip/hip_runtime.h>
#include <hip/hip_bf16.h>
#include <hip/hip_cooperative_groups.h>

namespace cg = cooperative_groups;

// ---------------------------------------------------------------------------
// SAGEConv: out = relu(concat(feature, mean_{src->dst}(feature)) @ W + b)
// N=10000 nodes, E=160000 edges, D_IN=512, D_OUT=512, K=1024
// Round 7: collapse 6 dispatches -> 3.
//   prep_kernel       = W-transpose + feat->bf16 convert (independent halves)
//   csr_gather_kernel = cooperative: zero/hist/parallel-scan/bucket/gather
//   gemm_kernel       = unchanged round-6 128x128 MFMA GEMM
// ---------------------------------------------------------------------------

#define N_NODES 10000
#define N_EDGES 160000
#define D_IN    512
#define D_OUT   512
#define K_DIM   1024

typedef float  f32x4  __attribute__((ext_vector_type(4)));
typedef __bf16 bf16x8 __attribute__((ext_vector_type(8)));
typedef unsigned short us8 __attribute__((ext_vector_type(8)));
typedef unsigned short us4 __attribute__((ext_vector_type(4)));

__device__ __forceinline__ unsigned short f2b(float f) {
    unsigned int u = __float_as_uint(f);
    unsigned int r = u + 0x7FFFu + ((u >> 16) & 1u);   // round-to-nearest-even
    return (unsigned short)(r >> 16);
}
__device__ __forceinline__ float b2f(unsigned short h) {
    return __uint_as_float(((unsigned int)h) << 16);
}
// global -> LDS direct 16B load. LDS dest is wave-uniform base + lane*16;
// global src is per-lane.
__device__ __forceinline__ void gl_lds16(const void* g, void* l) {
    auto gp = (const __attribute__((address_space(1))) unsigned int*)(uintptr_t)g;
    auto lp = (__attribute__((address_space(3))) unsigned int*)(uintptr_t)l;
    __builtin_amdgcn_global_load_lds(gp, lp, 16, 0, 0);
}

// ---------------------------------------------------------------------------
// Kernel 1: prep = [blocks 0..2499] feat fp32 -> Xb[:, :512] bf16
//                  [blocks 2500..3011] W [1024][512] fp32 -> WbT [512][1024] bf16
// ---------------------------------------------------------------------------
__global__ __launch_bounds__(256) void prep_kernel(const float* __restrict__ feat,
                                                   const float* __restrict__ W,
                                                   unsigned short* __restrict__ Xb,
                                                   unsigned short* __restrict__ WbT) {
    __shared__ float tile[32][33];
    const int b = blockIdx.x;
    const int t = threadIdx.x;
    if (b < 2500) {
        const int gid = b * 256 + t;
        const int row = gid >> 6;
        const int l   = gid & 63;
        const float4* s = (const float4*)(feat + (size_t)row * D_IN + l * 8);
        float4 v0 = s[0], v1 = s[1];
        us8 o;
        o[0] = f2b(v0.x); o[1] = f2b(v0.y); o[2] = f2b(v0.z); o[3] = f2b(v0.w);
        o[4] = f2b(v1.x); o[5] = f2b(v1.y); o[6] = f2b(v1.z); o[7] = f2b(v1.w);
        *(us8*)(Xb + (size_t)row * K_DIM + l * 8) = o;
    } else {
        const int bb = b - 2500;      // 0..511
        const int kt = bb & 31;       // 0..31
        const int nt = bb >> 5;       // 0..15
        const int c  = t & 31;
        const int r0 = t >> 5;
#pragma unroll
        for (int p = 0; p < 4; ++p) {
            int r = r0 + p * 8;
            tile[r][c] = W[(size_t)(kt * 32 + r) * D_OUT + nt * 32 + c];
        }
        __syncthreads();
#pragma unroll
        for (int p = 0; p < 4; ++p) {
            int r = r0 + p * 8;
            WbT[(size_t)(nt * 32 + r) * K_DIM + kt * 32 + c] = f2b(tile[c][r]);
        }
    }
}

// ---------------------------------------------------------------------------
// Kernel 2 (cooperative, 625 blocks x 256):
//   phase0: zero cnt
//   phase1: histogram of dst
//   phase2: parallel exclusive scan -> rowstart[10001], cursor
//   phase3: bucket fill eidx
//   phase4: gather-mean into Xb[:, 512:1024] (2 waves/node, grid-stride)
// ---------------------------------------------------------------------------
__global__ __launch_bounds__(256) void csr_gather_kernel(const int* __restrict__ src,
                                                         const int* __restrict__ dst,
                                                         unsigned short* __restrict__ Xb,
                                                         int* __restrict__ cnt,
                                                         int* __restrict__ rowstart,
                                                         int* __restrict__ cursor,
                                                         int* __restrict__ eidx,
                                                         int* __restrict__ blocksum,
                                                         int* __restrict__ blockoff) {
    cg::grid_group grid = cg::this_grid();
    __shared__ int sums[256];
    const int b = blockIdx.x;
    const int t = threadIdx.x;
    const int gid = b * 256 + t;

    // phase 0: zero cnt
    if (gid < N_NODES) cnt[gid] = 0;
    grid.sync();

    // phase 1: histogram
    atomicAdd(&cnt[dst[gid]], 1);        // gid in [0, 160000)
    grid.sync();

    // phase 2a: per-block exclusive scan over 256 nodes (blocks 0..39)
    if (b < 40) {
        const int node = b * 256 + t;
        const int v = (node < N_NODES) ? cnt[node] : 0;
        sums[t] = v;
        __syncthreads();
        for (int off = 1; off < 256; off <<= 1) {
            int x = (t >= off) ? sums[t - off] : 0;
            __syncthreads();
            sums[t] += x;
            __syncthreads();
        }
        if (node < N_NODES) rowstart[node] = sums[t] - v;   // block-local exclusive
        if (t == 255) blocksum[b] = sums[255];
    }
    grid.sync();

    // phase 2b: scan the 40 block sums (block 0)
    if (b == 0) {
        const int v = (t < 40) ? blocksum[t] : 0;
        sums[t] = v;
        __syncthreads();
        for (int off = 1; off < 256; off <<= 1) {
            int x = (t >= off) ? sums[t - off] : 0;
            __syncthreads();
            sums[t] += x;
            __syncthreads();
        }
        if (t < 40) blockoff[t] = sums[t] - v;
    }
    grid.sync();

    // phase 2c: apply block offsets; cursor = rowstart
    if (b < 40) {
        const int node = b * 256 + t;
        if (node < N_NODES) {
            int r = rowstart[node] + blockoff[b];
            rowstart[node] = r;
            cursor[node]   = r;
        }
    }
    if (b == 0 && t == 0) rowstart[N_NODES] = N_EDGES;
    grid.sync();

    // phase 3: bucket fill
    {
        int d = dst[gid];
        int slot = atomicAdd(&cursor[d], 1);
        eidx[slot] = src[gid];
    }
    grid.sync();

    // phase 4: gather-mean, 2 waves per node, 8B/lane, unroll-4, grid-stride
    {
        const int wv   = t >> 6;
        const int l    = t & 63;
        const int half = wv & 1;
        const int col  = half * 256 + l * 4;            // shorts
#pragma unroll
        for (int it = 0; it < 8; ++it) {
            const int node = (b + it * 625) * 2 + (wv >> 1);   // covers 0..9999
            const int beg  = rowstart[node];
            const int end  = rowstart[node + 1];
            float a0 = 0.f, a1 = 0.f, a2 = 0.f, a3 = 0.f;
            int j = beg;
            for (; j + 4 <= end; j += 4) {
                int s0 = eidx[j], s1 = eidx[j + 1], s2 = eidx[j + 2], s3 = eidx[j + 3];
                us4 v0 = *(const us4*)(Xb + (size_t)s0 * K_DIM + col);
                us4 v1 = *(const us4*)(Xb + (size_t)s1 * K_DIM + col);
                us4 v2 = *(const us4*)(Xb + (size_t)s2 * K_DIM + col);
                us4 v3 = *(const us4*)(Xb + (size_t)s3 * K_DIM + col);
                a0 += (b2f(v0[0]) + b2f(v1[0])) + (b2f(v2[0]) + b2f(v3[0]));
                a1 += (b2f(v0[1]) + b2f(v1[1])) + (b2f(v2[1]) + b2f(v3[1]));
                a2 += (b2f(v0[2]) + b2f(v1[2])) + (b2f(v2[2]) + b2f(v3[2]));
                a3 += (b2f(v0[3]) + b2f(v1[3])) + (b2f(v2[3]) + b2f(v3[3]));
            }
            for (; j < end; ++j) {
                int s0 = eidx[j];
                us4 v0 = *(const us4*)(Xb + (size_t)s0 * K_DIM + col);
                a0 += b2f(v0[0]); a1 += b2f(v0[1]); a2 += b2f(v0[2]); a3 += b2f(v0[3]);
            }
            float sc = 1.0f / fmaxf((float)(end - beg), 1.0f);
            us4 o;
            o[0] = f2b(a0 * sc); o[1] = f2b(a1 * sc);
            o[2] = f2b(a2 * sc); o[3] = f2b(a3 * sc);
            *(us4*)(Xb + (size_t)node * K_DIM + D_IN + col) = o;
        }
    }
}

// ---------------------------------------------------------------------------
// Kernel 3: GEMM  out[10000][512] = relu( Xb[10000][1024] @ WbT^T + b )
// 128x128 tile, BK=64, 4 waves (2x2), 64x64 wave-tile, mfma 16x16x32 bf16.
// Double-buffered LDS via global_load_lds(16B); XOR-swizzle (row&7)<<4 on the
// global SOURCE address (linear LDS dest) and on the ds_read address.
// Grid (79, 4) = 316 blocks; LDS 64KB -> 2 blocks/CU, all co-resident.
// ---------------------------------------------------------------------------
__global__ __launch_bounds__(256, 2) void gemm_kernel(const unsigned short* __restrict__ Xb,
                                                      const unsigned short* __restrict__ WbT,
                                                      const float* __restrict__ bias,
                                                      float* __restrict__ out) {
    __shared__ __align__(16) unsigned short As[2][8192];   // [128 rows][64 k] bf16
    __shared__ __align__(16) unsigned short Bs[2][8192];   // [128 cols][64 k] bf16

    const int tid = threadIdx.x;
    const int l   = tid & 63;
    const int w   = tid >> 6;
    const int wr  = w >> 1, wc = w & 1;
    const int brow = blockIdx.x * 128;
    const int bcol = blockIdx.y * 128;

    const int sub  = l >> 3;
    const int scol = ((l & 7) * 16) ^ (sub * 16);   // inverse swizzle on source
    const char* pa[4];
    const char* pb[4];
#pragma unroll
    for (int p = 0; p < 4; ++p) {
        int ra = brow + p * 32 + w * 8 + sub;
        ra = ra < N_NODES ? ra : N_NODES - 1;
        pa[p] = (const char*)Xb + (size_t)ra * 2048 + scol;
        pb[p] = (const char*)WbT + (size_t)(bcol + p * 32 + w * 8 + sub) * 2048 + scol;
    }

#define STAGE(buf, koff) do {                                          \
        gl_lds16(pa[0] + (koff), &As[buf][(0 * 32 + w * 8) * 64]);     \
        gl_lds16(pa[1] + (koff), &As[buf][(1 * 32 + w * 8) * 64]);     \
        gl_lds16(pa[2] + (koff), &As[buf][(2 * 32 + w * 8) * 64]);     \
        gl_lds16(pa[3] + (koff), &As[buf][(3 * 32 + w * 8) * 64]);     \
        gl_lds16(pb[0] + (koff), &Bs[buf][(0 * 32 + w * 8) * 64]);     \
        gl_lds16(pb[1] + (koff), &Bs[buf][(1 * 32 + w * 8) * 64]);     \
        gl_lds16(pb[2] + (koff), &Bs[buf][(2 * 32 + w * 8) * 64]);     \
        gl_lds16(pb[3] + (koff), &Bs[buf][(3 * 32 + w * 8) * 64]);     \
    } while (0)

    const int fr = l & 15;
    const int g  = l >> 4;
    const int sw = (fr & 7) * 16;
    const int h0 = ((g * 16)       ^ sw) >> 1;   // kh=0, in shorts
    const int h1 = ((64 + g * 16)  ^ sw) >> 1;   // kh=1

    f32x4 acc[4][4] = {};

    STAGE(0, 0);
    __syncthreads();
    int cur = 0;
#pragma unroll 2
    for (int t = 0; t < 16; ++t) {
        if (t < 15) STAGE(cur ^ 1, (t + 1) * 128);
        bf16x8 a[4][2], b[4][2];
#pragma unroll
        for (int m = 0; m < 4; ++m) {
            int r = (wr * 64 + m * 16 + fr) * 64;
            a[m][0] = *(const bf16x8*)&As[cur][r + h0];
            a[m][1] = *(const bf16x8*)&As[cur][r + h1];
        }
#pragma unroll
        for (int n = 0; n < 4; ++n) {
            int r = (wc * 64 + n * 16 + fr) * 64;
            b[n][0] = *(const bf16x8*)&Bs[cur][r + h0];
            b[n][1] = *(const bf16x8*)&Bs[cur][r + h1];
        }
#pragma unroll
        for (int kh = 0; kh < 2; ++kh)
#pragma unroll
            for (int m = 0; m < 4; ++m)
#pragma unroll
                for (int n = 0; n < 4; ++n)
                    acc[m][n] = __builtin_amdgcn_mfma_f32_16x16x32_bf16(a[m][kh], b[n][kh], acc[m][n], 0, 0, 0);
        __syncthreads();
        cur ^= 1;
    }
#undef STAGE

    // epilogue: bias + relu
#pragma unroll
    for (int n = 0; n < 4; ++n) {
        int col = bcol + wc * 64 + n * 16 + fr;
        float bv = bias[col];
#pragma unroll
        for (int m = 0; m < 4; ++m) {
            int row0 = brow + wr * 64 + m * 16 + g * 4;
#pragma unroll
            for (int j = 0; j < 4; ++j) {
                int row = row0 + j;
                if (row < N_NODES)
                    out[(size_t)row * D_OUT + col] = fmaxf(acc[m][n][j] + bv, 0.0f);
            }
        }
    }
}

// ---------------------------------------------------------------------------
// Launch.  ws layout (bytes):
//   [0,          20480000)  Xb        bf16 [10000][1024] (left=feat, right=mean)
//   [20480000,   20520000)  cnt       int  [10000]
//   [20520000,   20560016)  rowstart  int  [10001] (padded)
//   [20560016,   20600032)  cursor    int  [10001] (padded)
//   [20600032,   21240032)  eidx      int  [160000]
//   [21240032,   22288608)  WbT       bf16 [512][1024]
//   [22288608,   22288768)  blocksum  int  [40]
//   [22288768,   22288928)  blockoff  int  [40]
// ---------------------------------------------------------------------------
extern "C" void kernel_launch(void* const* d_in, const int* in_sizes, int n_in,
                              void* d_out, int out_size, void* d_ws, size_t ws_size,
                              hipStream_t stream) {
    const float* feat = (const float*)d_in[0];
    const int*   src  = (const int*)d_in[1];
    const int*   dst  = (const int*)d_in[2];
    const float* W    = (const float*)d_in[3];
    const float* bias = (const float*)d_in[4];
    float*       out  = (float*)d_out;

    char* ws = (char*)d_ws;
    unsigned short* Xb  = (unsigned short*)(ws);
    int*   cnt          = (int*)(ws + 20480000);
    int*   rowstart     = (int*)(ws + 20520000);
    int*   cursor       = (int*)(ws + 20560016);
    int*   eidx         = (int*)(ws + 20600032);
    unsigned short* WbT = (unsigned short*)(ws + 21240032);
    int*   blocksum     = (int*)(ws + 22288608);
    int*   blockoff     = (int*)(ws + 22288768);

    prep_kernel<<<3012, 256, 0, stream>>>(feat, W, Xb, WbT);

    void* args[] = {(void*)&src, (void*)&dst, (void*)&Xb, (void*)&cnt,
                    (void*)&rowstart, (void*)&cursor, (void*)&eidx,
                    (void*)&blocksum, (void*)&blockoff};
    hipLaunchCooperativeKernel((void*)csr_gather_kernel, dim3(625), dim3(256),
                               args, 0, stream);

    gemm_kernel<<<dim3(79, 4), 256, 0, stream>>>(Xb, WbT, bias, out);
}

// Round 8
// 89.244 us; speedup vs baseline: 5.6060x; 5.6060x over previous
//
#include <hip/hip_runtime.h>
#include <hip/hip_bf16.h>

// ---------------------------------------------------------------------------
// SAGEConv: out = relu(concat(feature, mean_{src->dst}(feature)) @ W + b)
// N=10000 nodes, E=160000 edges, D_IN=512, D_OUT=512, K=1024
// Round 8: revert round-7 cooperative fusion (grid.sync ~70us/each on 8-XCD
// MI355X!). Round-6 structure + XCD-aware GEMM block grouping so the 4
// col-tile blocks sharing an A-panel run on one XCD (A-panel L2-resident).
// ---------------------------------------------------------------------------

#define N_NODES 10000
#define N_EDGES 160000
#define D_IN    512
#define D_OUT   512
#define K_DIM   1024

typedef float  f32x4  __attribute__((ext_vector_type(4)));
typedef __bf16 bf16x8 __attribute__((ext_vector_type(8)));
typedef unsigned short us8 __attribute__((ext_vector_type(8)));
typedef unsigned short us4 __attribute__((ext_vector_type(4)));

__device__ __forceinline__ unsigned short f2b(float f) {
    unsigned int u = __float_as_uint(f);
    unsigned int r = u + 0x7FFFu + ((u >> 16) & 1u);   // round-to-nearest-even
    return (unsigned short)(r >> 16);
}
__device__ __forceinline__ float b2f(unsigned short h) {
    return __uint_as_float(((unsigned int)h) << 16);
}
// global -> LDS direct 16B load. LDS dest is wave-uniform base + lane*16;
// global src is per-lane.
__device__ __forceinline__ void gl_lds16(const void* g, void* l) {
    auto gp = (const __attribute__((address_space(1))) unsigned int*)(uintptr_t)g;
    auto lp = (__attribute__((address_space(3))) unsigned int*)(uintptr_t)l;
    __builtin_amdgcn_global_load_lds(gp, lp, 16, 0, 0);
}

// ---------------------------------------------------------------------------
// Kernel 1 (runs FIRST): W [1024][512] fp32 -> WbT [512][1024] bf16,
// fused cnt-zeroing (512 blocks x 20 ints = 10240 >= 10000).
// ---------------------------------------------------------------------------
__global__ __launch_bounds__(256) void wtrans_kernel(const float* __restrict__ W,
                                                     unsigned short* __restrict__ WbT,
                                                     int* __restrict__ cnt) {
    const int kt = blockIdx.x;   // 0..31
    const int nt = blockIdx.y;   // 0..15
    const int t  = threadIdx.x;

    const int bid = nt * 32 + kt;
    const int zi  = bid * 20 + t;
    if (t < 20 && zi < N_NODES) cnt[zi] = 0;

    __shared__ float tile[32][33];
    const int c  = t & 31;
    const int r0 = t >> 5;
#pragma unroll
    for (int p = 0; p < 4; ++p) {
        int r = r0 + p * 8;
        tile[r][c] = W[(size_t)(kt * 32 + r) * D_OUT + nt * 32 + c];
    }
    __syncthreads();
#pragma unroll
    for (int p = 0; p < 4; ++p) {
        int r = r0 + p * 8;
        WbT[(size_t)(nt * 32 + r) * K_DIM + kt * 32 + c] = f2b(tile[c][r]);
    }
}

// ---------------------------------------------------------------------------
// Kernel 2: feat fp32 -> Xb[:, :512] bf16, fused dst-histogram.
// ---------------------------------------------------------------------------
__global__ __launch_bounds__(256) void convert_hist_kernel(const float* __restrict__ feat,
                                                           const int* __restrict__ dst,
                                                           unsigned short* __restrict__ Xb,
                                                           int* __restrict__ cnt) {
    const int gid = blockIdx.x * 256 + threadIdx.x;
    const int row = gid >> 6;
    const int l   = gid & 63;
    const float4* s = (const float4*)(feat + (size_t)row * D_IN + l * 8);
    float4 v0 = s[0], v1 = s[1];
    us8 o;
    o[0] = f2b(v0.x); o[1] = f2b(v0.y); o[2] = f2b(v0.z); o[3] = f2b(v0.w);
    o[4] = f2b(v1.x); o[5] = f2b(v1.y); o[6] = f2b(v1.z); o[7] = f2b(v1.w);
    *(us8*)(Xb + (size_t)row * K_DIM + l * 8) = o;
    if (gid < N_EDGES) atomicAdd(&cnt[dst[gid]], 1);
}

// ---------------------------------------------------------------------------
// Kernel 3: exclusive scan cnt[10000] -> rowstart[10001], cursor = rowstart
// int4-vectorized walks (40 elems/thread, 16B aligned).
// ---------------------------------------------------------------------------
__global__ __launch_bounds__(256) void scan_kernel(const int* __restrict__ cnt,
                                                   int* __restrict__ rowstart,
                                                   int* __restrict__ cursor) {
    __shared__ int sums[256];
    const int t = threadIdx.x;
    const int base = t * 40;
    const int4* c4 = (const int4*)(cnt + base);
    int s = 0;
    if (base < N_NODES) {
#pragma unroll
        for (int i = 0; i < 10; ++i) {
            int4 v = c4[i];
            s += v.x + v.y + v.z + v.w;
        }
    }
    sums[t] = s;
    __syncthreads();
    for (int off = 1; off < 256; off <<= 1) {
        int v = (t >= off) ? sums[t - off] : 0;
        __syncthreads();
        sums[t] += v;
        __syncthreads();
    }
    int run = (t == 0) ? 0 : sums[t - 1];
    if (base < N_NODES) {
        int4* r4 = (int4*)(rowstart + base);
        int4* u4 = (int4*)(cursor + base);
#pragma unroll
        for (int i = 0; i < 10; ++i) {
            int4 v = c4[i];
            int4 o;
            o.x = run;  o.y = run + v.x;  o.z = run + v.x + v.y;
            o.w = run + v.x + v.y + v.z;
            run += v.x + v.y + v.z + v.w;
            r4[i] = o;
            u4[i] = o;
        }
    }
    if (t == 255) rowstart[N_NODES] = sums[255];
}

// ---------------------------------------------------------------------------
// Kernel 4: bucket fill.  eidx[cursor[d]++] = src[e]
// ---------------------------------------------------------------------------
__global__ __launch_bounds__(256) void bucket_kernel(const int* __restrict__ src,
                                                     const int* __restrict__ dst,
                                                     int* __restrict__ cursor,
                                                     int* __restrict__ eidx) {
    int e = blockIdx.x * 256 + threadIdx.x;
    int d = dst[e];
    int slot = atomicAdd(&cursor[d], 1);
    eidx[slot] = src[e];
}

// ---------------------------------------------------------------------------
// Kernel 5: gather-mean (bf16 in, bf16 out).  TWO waves per node (256 cols
// each, 8B/lane), unroll-4 over edges.
//   Xb[node][512:1024] = (1/max(deg,1)) * sum_j Xb[eidx[j]][0:512]
// ---------------------------------------------------------------------------
__global__ __launch_bounds__(256) void gather_kernel(unsigned short* Xb,
                                                     const int* __restrict__ eidx,
                                                     const int* __restrict__ rowstart) {
    const int wv   = threadIdx.x >> 6;
    const int l    = threadIdx.x & 63;
    const int node = blockIdx.x * 2 + (wv >> 1);
    const int half = wv & 1;
    const int col  = half * 256 + l * 4;            // shorts
    const int beg  = rowstart[node];
    const int end  = rowstart[node + 1];
    float a0 = 0.f, a1 = 0.f, a2 = 0.f, a3 = 0.f;
    int j = beg;
    for (; j + 4 <= end; j += 4) {
        int s0 = eidx[j], s1 = eidx[j + 1], s2 = eidx[j + 2], s3 = eidx[j + 3];
        us4 v0 = *(const us4*)(Xb + (size_t)s0 * K_DIM + col);
        us4 v1 = *(const us4*)(Xb + (size_t)s1 * K_DIM + col);
        us4 v2 = *(const us4*)(Xb + (size_t)s2 * K_DIM + col);
        us4 v3 = *(const us4*)(Xb + (size_t)s3 * K_DIM + col);
        a0 += (b2f(v0[0]) + b2f(v1[0])) + (b2f(v2[0]) + b2f(v3[0]));
        a1 += (b2f(v0[1]) + b2f(v1[1])) + (b2f(v2[1]) + b2f(v3[1]));
        a2 += (b2f(v0[2]) + b2f(v1[2])) + (b2f(v2[2]) + b2f(v3[2]));
        a3 += (b2f(v0[3]) + b2f(v1[3])) + (b2f(v2[3]) + b2f(v3[3]));
    }
    for (; j < end; ++j) {
        int s0 = eidx[j];
        us4 v0 = *(const us4*)(Xb + (size_t)s0 * K_DIM + col);
        a0 += b2f(v0[0]); a1 += b2f(v0[1]); a2 += b2f(v0[2]); a3 += b2f(v0[3]);
    }
    float sc = 1.0f / fmaxf((float)(end - beg), 1.0f);
    us4 o;
    o[0] = f2b(a0 * sc); o[1] = f2b(a1 * sc); o[2] = f2b(a2 * sc); o[3] = f2b(a3 * sc);
    *(us4*)(Xb + (size_t)node * K_DIM + D_IN + col) = o;
}

// ---------------------------------------------------------------------------
// Kernel 6: GEMM  out[10000][512] = relu( Xb[10000][1024] @ WbT^T + b )
// 128x128 tile, BK=64, 4 waves (2x2), 64x64 wave-tile, mfma 16x16x32 bf16.
// Double-buffered LDS via global_load_lds(16B); XOR-swizzle (row&7)<<4 on the
// global SOURCE address (linear LDS dest) and on the ds_read address.
// 1-D grid of 320 blocks, XCD-grouped: xcd = bid%8 (HW round-robin); each
// XCD's ranks pack the 4 col-tiles of one row-tile consecutively, so the
// 256KB A-panel stays L2-resident for its 4 blocks. 4 blocks idle-exit.
// ---------------------------------------------------------------------------
__global__ __launch_bounds__(256, 2) void gemm_kernel(const unsigned short* __restrict__ Xb,
                                                      const unsigned short* __restrict__ WbT,
                                                      const float* __restrict__ bias,
                                                      float* __restrict__ out) {
    __shared__ __align__(16) unsigned short As[2][8192];   // [128 rows][64 k] bf16
    __shared__ __align__(16) unsigned short Bs[2][8192];   // [128 cols][64 k] bf16

    // XCD-grouped decode: row-tile g (0..78), col-tile c (0..3)
    const int p    = blockIdx.x;      // 0..319
    const int xcd  = p & 7;
    const int rank = p >> 3;          // 0..39
    const int g    = xcd + 8 * (rank >> 2);
    const int c    = rank & 3;
    if (g >= 79) return;              // whole-block uniform exit (4 blocks)
    const int brow = g * 128;
    const int bcol = c * 128;

    const int tid = threadIdx.x;
    const int l   = tid & 63;
    const int w   = tid >> 6;
    const int wr  = w >> 1, wc = w & 1;

    const int sub  = l >> 3;
    const int scol = ((l & 7) * 16) ^ (sub * 16);   // inverse swizzle on source
    const char* pa[4];
    const char* pb[4];
#pragma unroll
    for (int q = 0; q < 4; ++q) {
        int ra = brow + q * 32 + w * 8 + sub;
        ra = ra < N_NODES ? ra : N_NODES - 1;
        pa[q] = (const char*)Xb + (size_t)ra * 2048 + scol;
        pb[q] = (const char*)WbT + (size_t)(bcol + q * 32 + w * 8 + sub) * 2048 + scol;
    }

#define STAGE(buf, koff) do {                                          \
        gl_lds16(pa[0] + (koff), &As[buf][(0 * 32 + w * 8) * 64]);     \
        gl_lds16(pa[1] + (koff), &As[buf][(1 * 32 + w * 8) * 64]);     \
        gl_lds16(pa[2] + (koff), &As[buf][(2 * 32 + w * 8) * 64]);     \
        gl_lds16(pa[3] + (koff), &As[buf][(3 * 32 + w * 8) * 64]);     \
        gl_lds16(pb[0] + (koff), &Bs[buf][(0 * 32 + w * 8) * 64]);     \
        gl_lds16(pb[1] + (koff), &Bs[buf][(1 * 32 + w * 8) * 64]);     \
        gl_lds16(pb[2] + (koff), &Bs[buf][(2 * 32 + w * 8) * 64]);     \
        gl_lds16(pb[3] + (koff), &Bs[buf][(3 * 32 + w * 8) * 64]);     \
    } while (0)

    const int fr = l & 15;
    const int gq = l >> 4;
    const int sw = (fr & 7) * 16;
    const int h0 = ((gq * 16)      ^ sw) >> 1;   // kh=0, in shorts
    const int h1 = ((64 + gq * 16) ^ sw) >> 1;   // kh=1

    f32x4 acc[4][4] = {};

    STAGE(0, 0);
    __syncthreads();
    int cur = 0;
#pragma unroll 2
    for (int t = 0; t < 16; ++t) {
        if (t < 15) STAGE(cur ^ 1, (t + 1) * 128);
        bf16x8 a[4][2], b[4][2];
#pragma unroll
        for (int m = 0; m < 4; ++m) {
            int r = (wr * 64 + m * 16 + fr) * 64;
            a[m][0] = *(const bf16x8*)&As[cur][r + h0];
            a[m][1] = *(const bf16x8*)&As[cur][r + h1];
        }
#pragma unroll
        for (int n = 0; n < 4; ++n) {
            int r = (wc * 64 + n * 16 + fr) * 64;
            b[n][0] = *(const bf16x8*)&Bs[cur][r + h0];
            b[n][1] = *(const bf16x8*)&Bs[cur][r + h1];
        }
#pragma unroll
        for (int kh = 0; kh < 2; ++kh)
#pragma unroll
            for (int m = 0; m < 4; ++m)
#pragma unroll
                for (int n = 0; n < 4; ++n)
                    acc[m][n] = __builtin_amdgcn_mfma_f32_16x16x32_bf16(a[m][kh], b[n][kh], acc[m][n], 0, 0, 0);
        __syncthreads();
        cur ^= 1;
    }
#undef STAGE

    // epilogue: bias + relu
#pragma unroll
    for (int n = 0; n < 4; ++n) {
        int col = bcol + wc * 64 + n * 16 + fr;
        float bv = bias[col];
#pragma unroll
        for (int m = 0; m < 4; ++m) {
            int row0 = brow + wr * 64 + m * 16 + gq * 4;
#pragma unroll
            for (int j = 0; j < 4; ++j) {
                int row = row0 + j;
                if (row < N_NODES)
                    out[(size_t)row * D_OUT + col] = fmaxf(acc[m][n][j] + bv, 0.0f);
            }
        }
    }
}

// ---------------------------------------------------------------------------
// Launch.  ws layout (bytes):
//   [0,          20480000)  Xb        bf16 [10000][1024] (left=feat, right=mean)
//   [20480000,   20520000)  cnt       int  [10000]
//   [20520000,   20560016)  rowstart  int  [10001] (padded)
//   [20560016,   20600032)  cursor    int  [10001] (padded)
//   [20600032,   21240032)  eidx      int  [160000]
//   [21240032,   22288608)  WbT       bf16 [512][1024]
// ---------------------------------------------------------------------------
extern "C" void kernel_launch(void* const* d_in, const int* in_sizes, int n_in,
                              void* d_out, int out_size, void* d_ws, size_t ws_size,
                              hipStream_t stream) {
    const float* feat = (const float*)d_in[0];
    const int*   src  = (const int*)d_in[1];
    const int*   dst  = (const int*)d_in[2];
    const float* W    = (const float*)d_in[3];
    const float* bias = (const float*)d_in[4];
    float*       out  = (float*)d_out;

    char* ws = (char*)d_ws;
    unsigned short* Xb  = (unsigned short*)(ws);
    int*   cnt          = (int*)(ws + 20480000);
    int*   rowstart     = (int*)(ws + 20520000);
    int*   cursor       = (int*)(ws + 20560016);
    int*   eidx         = (int*)(ws + 20600032);
    unsigned short* WbT = (unsigned short*)(ws + 21240032);

    wtrans_kernel<<<dim3(32, 16), 256, 0, stream>>>(W, WbT, cnt);   // zeroes cnt
    convert_hist_kernel<<<2500, 256, 0, stream>>>(feat, dst, Xb, cnt);
    scan_kernel<<<1, 256, 0, stream>>>(cnt, rowstart, cursor);
    bucket_kernel<<<N_EDGES / 256, 256, 0, stream>>>(src, dst, cursor, eidx);
    gather_kernel<<<5000, 256, 0, stream>>>(Xb, eidx, rowstart);
    gemm_kernel<<<320, 256, 0, stream>>>(Xb, WbT, bias, out);
}